// Round 1
// baseline (12098.696 us; speedup 1.0000x reference)
//
#include <hip/hip_runtime.h>

#define Bb 64
#define Ss 512
#define Ff 512
#define Hh 512
#define GW 2048  // 4H

using bf16x8 = __attribute__((ext_vector_type(8))) short;
using f32x4  = __attribute__((ext_vector_type(4))) float;
typedef __attribute__((ext_vector_type(4))) short short4v;
typedef unsigned short ushort_t;

__device__ __forceinline__ short f2bf(float f) {
  unsigned u = __builtin_bit_cast(unsigned, f);
  u = (u + 0x7FFFu + ((u >> 16) & 1u)) >> 16;
  return (short)u;
}
__device__ __forceinline__ float fsigmoid(float x) {
  return 1.f / (1.f + __expf(-x));
}
__device__ __forceinline__ float ftanh(float x) {
  x = fminf(fmaxf(x, -15.f), 15.f);
  float e = __expf(-2.f * x);
  return (1.f - e) / (1.f + e);
}

// ws layout:
//   [0, 262144)           : h double buffer  [2][2dirs][64][512] bf16
//   [262144, 262152)      : 2 barrier counters (per direction)
//   [262208, +33554432)   : optional x as bf16 [64][512][512]
#define HBUF_ELEMS (2 * Bb * Hh)          // one buffer: 2 dirs * 64 * 512
#define BAR_OFF    262144
#define XB_OFF     262208

__global__ void init_kernel(const float* __restrict__ x, ushort_t* hbuf0,
                            unsigned* bar, ushort_t* xb, int do_conv) {
  const int gtid = blockIdx.x * blockDim.x + threadIdx.x;
  const int gstride = gridDim.x * blockDim.x;
  if (gtid < 2) bar[gtid] = 0u;
  for (int i = gtid; i < HBUF_ELEMS; i += gstride) hbuf0[i] = 0;
  if (do_conv) {
    const float4* xv = (const float4*)x;
    const int n4 = Bb * Ss * Ff / 4;
    for (int i = gtid; i < n4; i += gstride) {
      float4 v = xv[i];
      short4v o;
      o[0] = f2bf(v.x); o[1] = f2bf(v.y); o[2] = f2bf(v.z); o[3] = f2bf(v.w);
      ((short4v*)xb)[i] = o;
    }
  }
}

template <int XPRE>
__global__ void __launch_bounds__(256, 1)
bilstm_kernel(const float* __restrict__ x, const ushort_t* __restrict__ xb,
              const float* __restrict__ Wf, const float* __restrict__ Uf,
              const float* __restrict__ bf, const float* __restrict__ Wb,
              const float* __restrict__ Ub, const float* __restrict__ bb,
              float* __restrict__ out, ushort_t* __restrict__ hbuf,
              unsigned* __restrict__ bar) {
  __shared__ float lds_part[4 * 64 * 20];  // [wave][row 0..63][pad 20]

  const int tid  = threadIdx.x;
  const int wg   = blockIdx.x;     // 0..255
  const int dir  = wg >> 7;        // 0 fwd, 1 bwd
  const int blk  = wg & 127;       // h-column block of 4
  const int wid  = tid >> 6;       // wave 0..3
  const int lane = tid & 63;
  const int n    = lane & 15;      // tile column 0..15
  const int kgrp = lane >> 4;      // 0..3
  const int wk0  = wid * 256;      // this wave's K base (K total = 1024)
  const bool is_h = (wid >= 2);    // waves 2,3 handle h@U (k in [512,1024))

  const float* W    = dir ? Wb : Wf;
  const float* U    = dir ? Ub : Uf;
  const float* bias = dir ? bb : bf;

  // ---- load weight B-fragments into registers (once) ----
  // tile col n -> gate = n>>2, local col = n&3 ; global gate col:
  const int gcol = (n >> 2) * Hh + blk * 4 + (n & 3);
  bf16x8 wfrag[8];
#pragma unroll
  for (int ks = 0; ks < 8; ++ks) {
    const int kb = wk0 + ks * 32 + kgrp * 8;
    bf16x8 w;
#pragma unroll
    for (int j = 0; j < 8; ++j) {
      const int k = kb + j;
      const float wv = (k < Ff) ? W[(size_t)k * GW + gcol]
                                : U[(size_t)(k - Ff) * GW + gcol];
      w[j] = f2bf(wv);
    }
    wfrag[ks] = w;
  }

  // ---- combine-phase constants ----
  const int crow = tid >> 2;          // batch row 0..63
  const int chl  = tid & 3;           // 0..3
  const int ccol = blk * 4 + chl;     // h column 0..511
  float bias_r[4];
#pragma unroll
  for (int g = 0; g < 4; ++g) bias_r[g] = bias[g * Hh + ccol];
  float c_reg = 0.f;

  ushort_t* hb0 = hbuf;
  ushort_t* hb1 = hbuf + HBUF_ELEMS;
  unsigned* mybar = bar + dir;

  float* out_hidden = out;
  float* out_h = out + (size_t)Bb * Ss * (2 * Hh);
  float* out_c = out_h + (size_t)Bb * (2 * Hh);

  for (int s = 0; s < Ss; ++s) {
    const int t_in = dir ? (Ss - 1 - s) : s;
    ushort_t* hcur = (s & 1) ? hb1 : hb0;
    ushort_t* hnxt = (s & 1) ? hb0 : hb1;

    // ---- GEMM partials: 64 rows x 16 cols, this wave's K slice ----
    f32x4 acc[4];
#pragma unroll
    for (int m = 0; m < 4; ++m) {
      bf16x8 af[8];
      if (is_h) {
        const ushort_t* hrow = hcur + (size_t)dir * Bb * Hh +
                               (size_t)(m * 16 + n) * Hh + (wk0 - Ff) + kgrp * 8;
#pragma unroll
        for (int ks = 0; ks < 8; ++ks)
          af[ks] = *(const bf16x8*)(hrow + ks * 32);
      } else if (XPRE) {
        const ushort_t* xrow = xb + ((size_t)(m * 16 + n) * Ss + t_in) * Ff +
                               wk0 + kgrp * 8;
#pragma unroll
        for (int ks = 0; ks < 8; ++ks)
          af[ks] = *(const bf16x8*)(xrow + ks * 32);
      } else {
        const float* xrow = x + ((size_t)(m * 16 + n) * Ss + t_in) * Ff +
                            wk0 + kgrp * 8;
#pragma unroll
        for (int ks = 0; ks < 8; ++ks) {
          const float4 p0 = *(const float4*)(xrow + ks * 32);
          const float4 p1 = *(const float4*)(xrow + ks * 32 + 4);
          bf16x8 a;
          a[0] = f2bf(p0.x); a[1] = f2bf(p0.y); a[2] = f2bf(p0.z); a[3] = f2bf(p0.w);
          a[4] = f2bf(p1.x); a[5] = f2bf(p1.y); a[6] = f2bf(p1.z); a[7] = f2bf(p1.w);
          af[ks] = a;
        }
      }
      f32x4 a4 = {0.f, 0.f, 0.f, 0.f};
#pragma unroll
      for (int ks = 0; ks < 8; ++ks)
        a4 = __builtin_amdgcn_mfma_f32_16x16x32_bf16(af[ks], wfrag[ks], a4, 0, 0, 0);
      acc[m] = a4;
    }
#pragma unroll
    for (int m = 0; m < 4; ++m)
#pragma unroll
      for (int r = 0; r < 4; ++r)
        lds_part[(wid * 64 + m * 16 + kgrp * 4 + r) * 20 + n] = acc[m][r];

    __syncthreads();

    // ---- combine: thread owns (batch row, h col) ----
    {
      float p[4];
#pragma unroll
      for (int g = 0; g < 4; ++g) {
        float sg = 0.f;
#pragma unroll
        for (int w = 0; w < 4; ++w)
          sg += lds_part[(w * 64 + crow) * 20 + g * 4 + chl];
        p[g] = sg + bias_r[g];
      }
      const float gi = fsigmoid(p[0]);
      const float gf = fsigmoid(p[1]);
      const float gg = ftanh(p[2]);
      const float go = fsigmoid(p[3]);
      c_reg = gf * c_reg + gi * gg;
      const float hv = go * ftanh(c_reg);

      hnxt[(size_t)dir * Bb * Hh + (size_t)crow * Hh + ccol] = (ushort_t)f2bf(hv);
      out_hidden[(size_t)crow * Ss * 2 * Hh + (size_t)s * 2 * Hh + dir * Hh + ccol] = hv;
      if (s == Ss - 1) {
        out_h[(size_t)crow * 2 * Hh + dir * Hh + ccol] = hv;
        if (dir == 0) {
          out_c[(size_t)crow * 2 * Hh + ccol] = c_reg;          // c_t = [c_fwd, c_fwd]
          out_c[(size_t)crow * 2 * Hh + Hh + ccol] = c_reg;
        }
      }
    }

    // ---- per-direction grid barrier (monotone counter) ----
    if (s != Ss - 1) {
      __syncthreads();
      if (tid == 0) {
        __hip_atomic_fetch_add(mybar, 1u, __ATOMIC_RELEASE, __HIP_MEMORY_SCOPE_AGENT);
        const unsigned tgt = (unsigned)(s + 1) * 128u;
        while (__hip_atomic_load(mybar, __ATOMIC_ACQUIRE, __HIP_MEMORY_SCOPE_AGENT) < tgt) {
          __builtin_amdgcn_s_sleep(1);
        }
      }
      __syncthreads();
    }
  }
}

extern "C" void kernel_launch(void* const* d_in, const int* in_sizes, int n_in,
                              void* d_out, int out_size, void* d_ws, size_t ws_size,
                              hipStream_t stream) {
  const float* x  = (const float*)d_in[0];
  const float* Wf = (const float*)d_in[1];
  const float* Uf = (const float*)d_in[2];
  const float* bf = (const float*)d_in[3];
  const float* Wb = (const float*)d_in[4];
  const float* Ub = (const float*)d_in[5];
  const float* bb = (const float*)d_in[6];
  float* out = (float*)d_out;

  ushort_t* hbuf = (ushort_t*)d_ws;
  unsigned* bar  = (unsigned*)((char*)d_ws + BAR_OFF);
  ushort_t* xb   = (ushort_t*)((char*)d_ws + XB_OFF);

  const size_t need_xpre = (size_t)XB_OFF + (size_t)Bb * Ss * Ff * 2;
  const int xpre = (ws_size >= need_xpre) ? 1 : 0;

  init_kernel<<<1024, 256, 0, stream>>>(x, hbuf, bar, xb, xpre);

  void* args[] = {(void*)&x,  (void*)&xb, (void*)&Wf, (void*)&Uf,
                  (void*)&bf, (void*)&Wb, (void*)&Ub, (void*)&bb,
                  (void*)&out, (void*)&hbuf, (void*)&bar};
  if (xpre) {
    hipLaunchCooperativeKernel((void*)bilstm_kernel<1>, dim3(256), dim3(256),
                               args, 0, stream);
  } else {
    hipLaunchCooperativeKernel((void*)bilstm_kernel<0>, dim3(256), dim3(256),
                               args, 0, stream);
  }
}

// Round 4
// 7359.734 us; speedup vs baseline: 1.6439x; 1.6439x over previous
//
#include <hip/hip_runtime.h>

#define Bb 64
#define Ss 512
#define Ff 512
#define Hh 512
#define GW 2048  // 4H
#define NWGD 128 // workgroups per direction (4 h-cols each)

using bf16x8 = __attribute__((ext_vector_type(8))) short;
using f32x4  = __attribute__((ext_vector_type(4))) float;
typedef __attribute__((ext_vector_type(4))) short short4v;
typedef unsigned short u16;

__device__ __forceinline__ short f2bf(float f) {
  unsigned u = __builtin_bit_cast(unsigned, f);
  u = (u + 0x7FFFu + ((u >> 16) & 1u)) >> 16;
  return (short)u;
}
__device__ __forceinline__ float fsigmoid(float x) {
  return 1.f / (1.f + __expf(-x));
}
__device__ __forceinline__ float ftanh(float x) {
  x = fminf(fmaxf(x, -15.f), 15.f);
  float e = __expf(-2.f * x);
  return (1.f - e) / (1.f + e);
}

// ws layout:
//   [0, 262144)         : h double buffer  [2][2dirs][64][512] bf16
//   [262144, 262400)    : barrier counters, one per direction, 64B apart
//   [262400, +33554432) : optional x as bf16 [64][512][512]
#define HBUF_ELEMS (2 * Bb * Hh)
#define BAR_OFF    262144
#define XB_OFF     262400

__global__ void init_kernel(const float* __restrict__ x, u16* hbuf0,
                            unsigned* bar, u16* xb, int do_conv) {
  const int gtid = blockIdx.x * blockDim.x + threadIdx.x;
  const int gstride = gridDim.x * blockDim.x;
  if (gtid < 2) bar[gtid * 16] = 0u;  // counters 64B apart
  for (int i = gtid; i < HBUF_ELEMS; i += gstride) hbuf0[i] = 0;
  if (do_conv) {
    const float4* xv = (const float4*)x;
    const int n4 = Bb * Ss * Ff / 4;
    for (int i = gtid; i < n4; i += gstride) {
      float4 v = xv[i];
      short4v o;
      o[0] = f2bf(v.x); o[1] = f2bf(v.y); o[2] = f2bf(v.z); o[3] = f2bf(v.w);
      ((short4v*)xb)[i] = o;
    }
  }
}

template <int XPRE>
__global__ void __launch_bounds__(256, 2)
bilstm_kernel(const float* __restrict__ x, const u16* __restrict__ xb,
              const float* __restrict__ Wf, const float* __restrict__ Uf,
              const float* __restrict__ bfp, const float* __restrict__ Wb,
              const float* __restrict__ Ub, const float* __restrict__ bbp,
              float* __restrict__ out, u16* __restrict__ hbuf,
              unsigned* __restrict__ bar) {
  const int tid = threadIdx.x, wg = blockIdx.x;
  const int dir = wg & 1;        // interleaved so each dir spans XCDs evenly
  const int blk = wg >> 1;       // 0..127, owns h-cols [blk*4, blk*4+4)
  const int wid = tid >> 6, lane = tid & 63;
  const int n = lane & 15, kgrp = lane >> 4;

  const float* W    = dir ? Wb : Wf;
  const float* Uu   = dir ? Ub : Uf;
  const float* bias = dir ? bbp : bfp;

  // one 16-col B-tile: col n -> gate g = n>>2, h-col = blk*4 + (n&3)
  const int gc = (n >> 2) * Hh + blk * 4 + (n & 3);
  const float b_own = bias[gc];

  // ---- weight fragments in registers (once): 16 k-slices each ----
  bf16x8 wfW[16], wfU[16];
#pragma unroll
  for (int ks = 0; ks < 16; ++ks) {
    bf16x8 w0, u0;
#pragma unroll
    for (int j = 0; j < 8; ++j) {
      const int k = ks * 32 + kgrp * 8 + j;
      w0[j] = f2bf(W[(size_t)k * GW + gc]);
      u0[j] = f2bf(Uu[(size_t)k * GW + gc]);
    }
    wfW[ks] = w0;
    wfU[ks] = u0;
  }

  const int arow = wid * 16 + n;  // batch row for A-fragments
  float c_reg[4] = {0.f, 0.f, 0.f, 0.f};

  u16* hb0 = hbuf;
  u16* hb1 = hbuf + HBUF_ELEMS;
  unsigned* mybar = bar + dir * 16;  // 64B apart

  float* out_hidden = out;
  float* out_h = out + (size_t)Bb * Ss * 2 * Hh;
  float* out_c = out_h + (size_t)Bb * 2 * Hh;

  bf16x8 afx[16];
  f32x4 accX;

  auto issue_x = [&](int t) {
    if (XPRE) {
      const u16* xbase = xb + ((size_t)arow * Ss + t) * Ff + kgrp * 8;
#pragma unroll
      for (int ks = 0; ks < 16; ++ks)
        afx[ks] = *(const bf16x8*)(xbase + ks * 32);
    }
  };
  auto finish_x = [&](int t) {
    f32x4 t0 = {0.f, 0.f, 0.f, 0.f};
    const float* xrow = x + ((size_t)arow * Ss + t) * Ff + kgrp * 8;
#pragma unroll
    for (int ks = 0; ks < 16; ++ks) {
      bf16x8 a;
      if (XPRE) {
        a = afx[ks];
      } else {
        const f32x4 p0 = *(const f32x4*)(xrow + ks * 32);
        const f32x4 p1 = *(const f32x4*)(xrow + ks * 32 + 4);
#pragma unroll
        for (int j = 0; j < 4; ++j) {
          a[j] = f2bf(p0[j]);
          a[j + 4] = f2bf(p1[j]);
        }
      }
      t0 = __builtin_amdgcn_mfma_f32_16x16x32_bf16(a, wfW[ks], t0, 0, 0, 0);
    }
    accX = t0;
  };

  // prologue: x-part for step 0
  {
    const int t0i = dir ? (Ss - 1) : 0;
    issue_x(t0i);
    finish_x(t0i);
  }

  for (int s = 0; s < Ss; ++s) {
    u16* hcur = (s & 1) ? hb1 : hb0;
    u16* hnxt = (s & 1) ? hb0 : hb1;
    const bool last = (s == Ss - 1);

    // ---- h@U chained onto x@W accumulator ----
    const u16* hbase = hcur + (size_t)dir * Bb * Hh + (size_t)arow * Hh + kgrp * 8;
    f32x4 acc = accX;
#pragma unroll
    for (int ks = 0; ks < 16; ++ks) {
      const bf16x8 ah = *(const bf16x8*)(hbase + ks * 32);
      acc = __builtin_amdgcn_mfma_f32_16x16x32_bf16(ah, wfU[ks], acc, 0, 0, 0);
    }

    const int tnext = dir ? (Ss - 2 - s) : (s + 1);
    if (!last) issue_x(tnext);  // loads in flight under combine

    // ---- wave-local gate combine (valid in lanes n<4) ----
    float hv[4];
#pragma unroll
    for (int r = 0; r < 4; ++r) {
      const float a = acc[r] + b_own;
      const float act = ((n >> 2) == 2) ? ftanh(a) : fsigmoid(a);
      const float f4  = __shfl_xor(act, 4);   // lane n<4: forget gate
      const float g8  = __shfl_xor(act, 8);   // lane n<4: cell gate
      const float o12 = __shfl_xor(act, 12);  // lane n<4: output gate
      c_reg[r] = f4 * c_reg[r] + act * g8;
      hv[r] = o12 * ftanh(c_reg[r]);
    }
    float hnb[4];
#pragma unroll
    for (int r = 0; r < 4; ++r) hnb[r] = __shfl_xor(hv[r], 1);
    float cnb[4];
    if (last) {
#pragma unroll
      for (int r = 0; r < 4; ++r) cnb[r] = __shfl_xor(c_reg[r], 1);
    }

    if ((n & 1) == 0 && n < 4) {  // lanes n in {0,2} own col pair (c, c+1)
      const int col = blk * 4 + n;
#pragma unroll
      for (int r = 0; r < 4; ++r) {
        const int row = wid * 16 + kgrp * 4 + r;
        const unsigned hp = (unsigned)(unsigned short)f2bf(hv[r]) |
                            ((unsigned)(unsigned short)f2bf(hnb[r]) << 16);
        *(unsigned*)(hnxt + (size_t)dir * Bb * Hh + (size_t)row * Hh + col) = hp;
        float2 o2;
        o2.x = hv[r]; o2.y = hnb[r];
        *(float2*)(out_hidden + (size_t)row * Ss * 2 * Hh + (size_t)s * 2 * Hh +
                   (size_t)dir * Hh + col) = o2;
        if (last) {
          *(float2*)(out_h + (size_t)row * 2 * Hh + (size_t)dir * Hh + col) = o2;
          if (dir == 0) {  // bug-faithful: c_t = [c_fwd, c_fwd]
            float2 c2;
            c2.x = c_reg[r]; c2.y = cnb[r];
            *(float2*)(out_c + (size_t)row * 2 * Hh + col) = c2;
            *(float2*)(out_c + (size_t)row * 2 * Hh + Hh + col) = c2;
          }
        }
      }
    }

    // ---- x@W for next step, then the R1-proven grid barrier ----
    if (!last) {
      finish_x(tnext);
      __syncthreads();  // drains all waves' h stores before arrive
      if (tid == 0) {
        __hip_atomic_fetch_add(mybar, 1u, __ATOMIC_RELEASE, __HIP_MEMORY_SCOPE_AGENT);
        const unsigned tgt = (unsigned)(s + 1) * NWGD;
        while (__hip_atomic_load(mybar, __ATOMIC_ACQUIRE, __HIP_MEMORY_SCOPE_AGENT) < tgt)
          __builtin_amdgcn_s_sleep(1);
      }
      __syncthreads();
    }
  }
}

extern "C" void kernel_launch(void* const* d_in, const int* in_sizes, int n_in,
                              void* d_out, int out_size, void* d_ws, size_t ws_size,
                              hipStream_t stream) {
  const float* x  = (const float*)d_in[0];
  const float* Wf = (const float*)d_in[1];
  const float* Uf = (const float*)d_in[2];
  const float* bf = (const float*)d_in[3];
  const float* Wb = (const float*)d_in[4];
  const float* Ub = (const float*)d_in[5];
  const float* bb = (const float*)d_in[6];
  float* out = (float*)d_out;

  u16* hbuf     = (u16*)d_ws;
  unsigned* bar = (unsigned*)((char*)d_ws + BAR_OFF);
  u16* xb       = (u16*)((char*)d_ws + XB_OFF);

  const size_t need_xpre = (size_t)XB_OFF + (size_t)Bb * Ss * Ff * 2;
  const int xpre = (ws_size >= need_xpre) ? 1 : 0;

  init_kernel<<<1024, 256, 0, stream>>>(x, hbuf, bar, xb, xpre);

  void* args[] = {(void*)&x,  (void*)&xb, (void*)&Wf, (void*)&Uf,
                  (void*)&bf, (void*)&Wb, (void*)&Ub, (void*)&bb,
                  (void*)&out, (void*)&hbuf, (void*)&bar};
  hipError_t err;
  if (xpre) {
    err = hipLaunchCooperativeKernel((void*)bilstm_kernel<1>, dim3(2 * NWGD),
                                     dim3(256), args, 0, stream);
  } else {
    err = hipLaunchCooperativeKernel((void*)bilstm_kernel<0>, dim3(2 * NWGD),
                                     dim3(256), args, 0, stream);
  }
  if (err != hipSuccess) {
    // fallback: plain launch; grid (256 WGs, 2 waves/SIMD occupancy) is fully
    // co-resident on 256 CUs, and the barrier is a monotone counter.
    if (xpre) {
      bilstm_kernel<1><<<dim3(2 * NWGD), dim3(256), 0, stream>>>(
          x, xb, Wf, Uf, bf, Wb, Ub, bb, out, hbuf, bar);
    } else {
      bilstm_kernel<0><<<dim3(2 * NWGD), dim3(256), 0, stream>>>(
          x, xb, Wf, Uf, bf, Wb, Ub, bb, out, hbuf, bar);
    }
  }
}